// Round 3
// baseline (299.719 us; speedup 1.0000x reference)
//
#include <hip/hip_runtime.h>
#include <hip/hip_bf16.h>
#include <stdint.h>

typedef __attribute__((ext_vector_type(8))) short bf16x8;
typedef __attribute__((ext_vector_type(4))) short short4v;
typedef __attribute__((ext_vector_type(4))) float f32x4;

#define DEV static __device__ __forceinline__

DEV short f32_to_bf16_bits(float x) {
  union { __hip_bfloat16 h; short s; } u;
  u.h = __float2bfloat16(x);
  return u.s;
}

// Stage a 128x64 tile (rows row0.., k k0..k0+63) into padded LDS [128][72] bf16.
// F32: source is fp32, convert to bf16 on the fly. Else: source already bf16.
template<bool F32>
DEV void stage_tile(const void* __restrict__ G, int ld, long row0, int k0,
                    short* S, int tid) {
  if constexpr (F32) {
    const float* g = (const float*)G;
#pragma unroll
    for (int c = 0; c < 8; ++c) {
      int ci = c * 256 + tid;
      int row = ci >> 4, fc = ci & 15;          // 16 float4-chunks per row
      float4 v = *(const float4*)(g + (row0 + row) * (long)ld + k0 + fc * 4);
      short4v s;
      s[0] = f32_to_bf16_bits(v.x);
      s[1] = f32_to_bf16_bits(v.y);
      s[2] = f32_to_bf16_bits(v.z);
      s[3] = f32_to_bf16_bits(v.w);
      *(short4v*)(S + row * 72 + fc * 4) = s;   // 8B store, aligned
    }
  } else {
    const __hip_bfloat16* g = (const __hip_bfloat16*)G;
#pragma unroll
    for (int c = 0; c < 4; ++c) {
      int ci = c * 256 + tid;
      int row = ci >> 3, ch = ci & 7;           // 8 bf16x8-chunks per row
      bf16x8 v = *(const bf16x8*)(g + (row0 + row) * (long)ld + k0 + ch * 8);
      *(bf16x8*)(S + row * 72 + ch * 8) = v;    // 16B store, aligned (144|16)
    }
  }
}

// ---------------------------------------------------------------------------
// C[M,N] = A[M,K] @ Bt[N,K]^T. 128x128 tile, BK=64, 4 waves (2x2 of 64x64).
// Padded LDS stride 72 (2-way bank conflict = free). Reg-staged loads.
// ---------------------------------------------------------------------------
template<bool AF32, bool BF32, bool CF32>
__global__ __launch_bounds__(256) void gemm_bt(const void* __restrict__ Ap,
                                               const void* __restrict__ Bp,
                                               void* __restrict__ Cp,
                                               int M, int N, int K) {
  __shared__ short sA[128 * 72];
  __shared__ short sB[128 * 72];
  const int tid = threadIdx.x;
  const int lane = tid & 63;
  const int w = tid >> 6;
  const int wr = w >> 1, wc = w & 1;
  const int l15 = lane & 15, l4 = lane >> 4;
  const long m0 = (long)blockIdx.y * 128, n0 = (long)blockIdx.x * 128;

  f32x4 acc[4][4] = {};

  for (int k0 = 0; k0 < K; k0 += 64) {
    __syncthreads();
    stage_tile<AF32>(Ap, K, m0, k0, sA, tid);
    stage_tile<BF32>(Bp, K, n0, k0, sB, tid);
    __syncthreads();
#pragma unroll
    for (int ks = 0; ks < 2; ++ks) {
      bf16x8 av[4], bv[4];
#pragma unroll
      for (int i = 0; i < 4; ++i) {
        int row = wr * 64 + i * 16 + l15;
        av[i] = *(const bf16x8*)(sA + row * 72 + (ks * 4 + l4) * 8);
      }
#pragma unroll
      for (int i = 0; i < 4; ++i) {
        int row = wc * 64 + i * 16 + l15;
        bv[i] = *(const bf16x8*)(sB + row * 72 + (ks * 4 + l4) * 8);
      }
#pragma unroll
      for (int mi = 0; mi < 4; ++mi)
#pragma unroll
        for (int ni = 0; ni < 4; ++ni)
          acc[mi][ni] = __builtin_amdgcn_mfma_f32_16x16x32_bf16(av[mi], bv[ni], acc[mi][ni], 0, 0, 0);
    }
  }
  // epilogue: C/D layout col=lane&15, row=(lane>>4)*4+reg
#pragma unroll
  for (int mi = 0; mi < 4; ++mi)
#pragma unroll
    for (int r = 0; r < 4; ++r) {
      long row = m0 + wr * 64 + mi * 16 + l4 * 4 + r;
#pragma unroll
      for (int ni = 0; ni < 4; ++ni) {
        long col = n0 + wc * 64 + ni * 16 + l15;
        if constexpr (CF32)
          ((float*)Cp)[row * (long)N + col] = acc[mi][ni][r];
        else
          ((__hip_bfloat16*)Cp)[row * (long)N + col] = __float2bfloat16(acc[mi][ni][r]);
      }
    }
}

// ---------------------------------------------------------------------------
// Flash attention with ALiBi + causal. qkv (bf16 workspace) [B*T][3072],
// col = which*1024 + h*64 + d. One block = (b,h) x 128 q-rows; 4 waves x 32
// q-rows; KVBLK=64. Output attn (bf16 workspace) [B*T][1024] at col h*64+d.
// ---------------------------------------------------------------------------
__global__ __launch_bounds__(256) void attn_fwd(const __hip_bfloat16* __restrict__ qkv,
                                                __hip_bfloat16* __restrict__ O) {
  constexpr int T = 2048;
  constexpr int LDQ = 3072;
  const int b = blockIdx.y >> 4;
  const int h = blockIdx.y & 15;
  const int q0 = blockIdx.x * 128;
  const int tid = threadIdx.x;
  const int lane = tid & 63;
  const int w = tid >> 6;
  const int l15 = lane & 15, l4 = lane >> 4;

  __shared__ short sKp[64 * 72];     // [kv][d] padded
  __shared__ short sVT[64 * 72];     // [d][kv] padded
  __shared__ short sP[4][32 * 72];   // per-wave P repack [qloc][kv] padded

  const float slope = exp2f(-0.5f * (float)(h + 1));  // 2^(-8/16*(h+1))
  const float scale = 0.125f;                          // 1/sqrt(64)
  const long base_bt = (long)b * T;

  // Q fragments hoisted to registers: [mf][ks]; A-frag row=lane&15, k=l4*8+j
  bf16x8 qf[2][2];
#pragma unroll
  for (int mf = 0; mf < 2; ++mf)
#pragma unroll
    for (int ks = 0; ks < 2; ++ks) {
      long qrow = base_bt + q0 + w * 32 + mf * 16 + l15;
      qf[mf][ks] = *(const bf16x8*)(qkv + qrow * LDQ + h * 64 + ks * 32 + l4 * 8);
    }

  f32x4 oacc[2][4] = {};
  float mrun[2][4], lrun[2][4];
#pragma unroll
  for (int mf = 0; mf < 2; ++mf)
#pragma unroll
    for (int r = 0; r < 4; ++r) { mrun[mf][r] = -1e30f; lrun[mf][r] = 0.f; }

  const int kv_end = q0 + 128;  // causal: only kv < q0+128 needed
  for (int kv0 = 0; kv0 < kv_end; kv0 += 64) {
    __syncthreads();
    // stage K [64][72]: reg-staged bf16x8 loads
#pragma unroll
    for (int c = 0; c < 2; ++c) {
      int ci = c * 256 + tid;
      int row = ci >> 3, ch = ci & 7;
      bf16x8 kv8 = *(const bf16x8*)(qkv + (base_bt + kv0 + row) * LDQ + 1024 + h * 64 + ch * 8);
      *(bf16x8*)(sKp + row * 72 + ch * 8) = kv8;
    }
    // stage V^T [64][72]: thread reads V[kv=lane][d0..d0+7], scatters transposed
#pragma unroll
    for (int i = 0; i < 2; ++i) {
      int d0 = 8 * (w + 4 * i);
      bf16x8 v = *(const bf16x8*)(qkv + (base_bt + kv0 + lane) * LDQ + 2048 + h * 64 + d0);
#pragma unroll
      for (int j = 0; j < 8; ++j)
        sVT[(d0 + j) * 72 + lane] = v[j];
    }
    __syncthreads();

    // S = Q @ K^T : frags [mf][nf], C-layout (q_row=(l>>4)*4+r, kv_col=l&15)
    f32x4 s[2][4] = {};
#pragma unroll
    for (int ks = 0; ks < 2; ++ks) {
      bf16x8 kf[4];
#pragma unroll
      for (int nf = 0; nf < 4; ++nf) {
        int row = nf * 16 + l15;
        kf[nf] = *(const bf16x8*)(sKp + row * 72 + (ks * 4 + l4) * 8);
      }
#pragma unroll
      for (int mf = 0; mf < 2; ++mf)
#pragma unroll
        for (int nf = 0; nf < 4; ++nf)
          s[mf][nf] = __builtin_amdgcn_mfma_f32_16x16x32_bf16(qf[mf][ks], kf[nf], s[mf][nf], 0, 0, 0);
    }

    // online softmax: scale + alibi + causal mask, rowwise over 16-lane groups
#pragma unroll
    for (int mf = 0; mf < 2; ++mf)
#pragma unroll
      for (int r = 0; r < 4; ++r) {
        int q = q0 + w * 32 + mf * 16 + l4 * 4 + r;
        float sv[4];
#pragma unroll
        for (int nf = 0; nf < 4; ++nf) {
          int kv = kv0 + nf * 16 + l15;
          float val = s[mf][nf][r] * scale - slope * (float)(q - kv);
          sv[nf] = (kv <= q) ? val : -1e30f;
        }
        float mx = fmaxf(fmaxf(sv[0], sv[1]), fmaxf(sv[2], sv[3]));
#pragma unroll
        for (int off = 1; off < 16; off <<= 1)
          mx = fmaxf(mx, __shfl_xor(mx, off, 64));
        float mnew = fmaxf(mrun[mf][r], mx);
        float f = __expf(mrun[mf][r] - mnew);
        mrun[mf][r] = mnew;
        float sum = 0.f;
        int qloc = mf * 16 + l4 * 4 + r;
#pragma unroll
        for (int nf = 0; nf < 4; ++nf) {
          float p = __expf(sv[nf] - mnew);
          sum += p;
          sP[w][qloc * 72 + nf * 16 + l15] = f32_to_bf16_bits(p);
        }
#pragma unroll
        for (int off = 1; off < 16; off <<= 1)
          sum += __shfl_xor(sum, off, 64);
        lrun[mf][r] = lrun[mf][r] * f + sum;
#pragma unroll
        for (int nd = 0; nd < 4; ++nd)
          oacc[mf][nd][r] *= f;
      }

    // fence per-wave P writes before A-frag reads (rule 18)
    asm volatile("s_waitcnt lgkmcnt(0)" ::: "memory");
    __builtin_amdgcn_sched_barrier(0);

    // O += P @ V  (A = P from sP, B = V via sVT rows)
#pragma unroll
    for (int ks = 0; ks < 2; ++ks) {
      bf16x8 pf[2], vf[4];
#pragma unroll
      for (int mf = 0; mf < 2; ++mf)
        pf[mf] = *(const bf16x8*)(sP[w] + (mf * 16 + l15) * 72 + ks * 32 + l4 * 8);
#pragma unroll
      for (int nd = 0; nd < 4; ++nd)
        vf[nd] = *(const bf16x8*)(sVT + (nd * 16 + l15) * 72 + ks * 32 + l4 * 8);
#pragma unroll
      for (int mf = 0; mf < 2; ++mf)
#pragma unroll
        for (int nd = 0; nd < 4; ++nd)
          oacc[mf][nd] = __builtin_amdgcn_mfma_f32_16x16x32_bf16(pf[mf], vf[nd], oacc[mf][nd], 0, 0, 0);
    }
  }

  // epilogue: O / l
#pragma unroll
  for (int mf = 0; mf < 2; ++mf)
#pragma unroll
    for (int r = 0; r < 4; ++r) {
      long q = base_bt + q0 + w * 32 + mf * 16 + l4 * 4 + r;
      float inv = 1.0f / lrun[mf][r];
#pragma unroll
      for (int nd = 0; nd < 4; ++nd) {
        int d = nd * 16 + l15;
        O[q * 1024 + h * 64 + d] = __float2bfloat16(oacc[mf][nd][r] * inv);
      }
    }
}

extern "C" void kernel_launch(void* const* d_in, const int* in_sizes, int n_in,
                              void* d_out, int out_size, void* d_ws, size_t ws_size,
                              hipStream_t stream) {
  const float* x    = (const float*)d_in[0];   // [2,2048,1024] fp32
  const float* Wqkv = (const float*)d_in[1];   // [3072,1024] fp32
  const float* Wout = (const float*)d_in[2];   // [1024,1024] fp32
  float* out = (float*)d_out;                  // [2,2048,1024] fp32

  __hip_bfloat16* qkv_ws  = (__hip_bfloat16*)d_ws;               // [4096,3072] bf16
  __hip_bfloat16* attn_ws = qkv_ws + (size_t)4096 * 3072;        // [4096,1024] bf16

  dim3 blk(256);
  // qkv = x @ W_qkv^T : M=4096 N=3072 K=1024  (fp32 in -> bf16 out)
  gemm_bt<true, true, false><<<dim3(3072 / 128, 4096 / 128), blk, 0, stream>>>(
      x, Wqkv, qkv_ws, 4096, 3072, 1024);
  // attention: grid (qtile=16, b*H=32), bf16 -> bf16
  attn_fwd<<<dim3(16, 32), blk, 0, stream>>>(qkv_ws, attn_ws);
  // out = attn @ W_out^T : M=4096 N=1024 K=1024  (bf16/fp32 in -> fp32 out)
  gemm_bt<false, true, true><<<dim3(1024 / 128, 4096 / 128), blk, 0, stream>>>(
      attn_ws, Wout, out, 4096, 1024, 1024);
}

// Round 5
// 212.893 us; speedup vs baseline: 1.4078x; 1.4078x over previous
//
#include <hip/hip_runtime.h>
#include <hip/hip_bf16.h>
#include <stdint.h>

typedef __attribute__((ext_vector_type(8))) short bf16x8;
typedef __attribute__((ext_vector_type(4))) short short4v;
typedef __attribute__((ext_vector_type(4))) float f32x4;

#define DEV static __device__ __forceinline__

DEV void load_lds16(const void* g, void* l) {
  __builtin_amdgcn_global_load_lds((const __attribute__((address_space(1))) char*)g,
                                   (__attribute__((address_space(3))) char*)l, 16, 0, 0);
}

DEV short f32_to_bf16_bits(float x) {
  union { __hip_bfloat16 h; short s; } u;
  u.h = __float2bfloat16(x);
  return u.s;
}
DEV float bf16_bits_to_f32(short s) {
  union { float f; unsigned u; } u;
  u.u = ((unsigned)(unsigned short)s) << 16;
  return u.f;
}

// ---------------------------------------------------------------------------
// fp32 -> bf16 pre-convert for x, W_qkv, W_out (one dispatch, 3 segments).
// ---------------------------------------------------------------------------
#define NX4 1048576   // 4096*1024/4
#define NQ4 786432    // 3072*1024/4
#define NW4 262144    // 1024*1024/4
__global__ __launch_bounds__(256) void conv_f32_bf16(const float4* __restrict__ x,
                                                     const float4* __restrict__ wq,
                                                     const float4* __restrict__ wo,
                                                     short4v* __restrict__ ox,
                                                     short4v* __restrict__ oq,
                                                     short4v* __restrict__ ow) {
  int i = blockIdx.x * 256 + threadIdx.x;
  const float4* src; short4v* dst; int j;
  if (i < NX4)            { src = x;  dst = ox; j = i; }
  else if (i < NX4 + NQ4) { src = wq; dst = oq; j = i - NX4; }
  else                    { src = wo; dst = ow; j = i - NX4 - NQ4; }
  float4 v = src[j];
  short4v s;
  s[0] = f32_to_bf16_bits(v.x); s[1] = f32_to_bf16_bits(v.y);
  s[2] = f32_to_bf16_bits(v.z); s[3] = f32_to_bf16_bits(v.w);
  dst[j] = s;
}

// ---------------------------------------------------------------------------
// C[M,N] = A[M,K] @ Bt[N,K]^T, A/Bt row-major bf16. 128x128 tile, BK=64,
// 4 waves (2x2 of 64x64). global_load_lds width 16, XOR chunk swizzle:
// LDS[row][cc] = G[row][cc ^ (row&7)]; read applies same XOR (involution).
// ---------------------------------------------------------------------------
template<bool CF32>
__global__ __launch_bounds__(256) void gemm_bt(const __hip_bfloat16* __restrict__ A,
                                               const __hip_bfloat16* __restrict__ Bt,
                                               void* __restrict__ Cp,
                                               int M, int N, int K) {
  __shared__ short sA[128 * 64];
  __shared__ short sB[128 * 64];
  const int tid = threadIdx.x;
  const int lane = tid & 63;
  const int w = tid >> 6;
  const int wr = w >> 1, wc = w & 1;
  const int l15 = lane & 15, l4 = lane >> 4;
  const long m0 = (long)blockIdx.y * 128, n0 = (long)blockIdx.x * 128;

  f32x4 acc[4][4] = {};

  for (int k0 = 0; k0 < K; k0 += 64) {
    __syncthreads();
#pragma unroll
    for (int c = 0; c < 4; ++c) {
      int ci = c * 256 + tid;
      int row = ci >> 3;
      int sc = (ci & 7) ^ (row & 7);
      load_lds16(A + (m0 + row) * (long)K + k0 + sc * 8, (char*)sA + c * 4096 + w * 1024);
    }
#pragma unroll
    for (int c = 0; c < 4; ++c) {
      int ci = c * 256 + tid;
      int row = ci >> 3;
      int sc = (ci & 7) ^ (row & 7);
      load_lds16(Bt + (n0 + row) * (long)K + k0 + sc * 8, (char*)sB + c * 4096 + w * 1024);
    }
    __syncthreads();
#pragma unroll
    for (int ks = 0; ks < 2; ++ks) {
      bf16x8 av[4], bv[4];
#pragma unroll
      for (int i = 0; i < 4; ++i) {
        int row = wr * 64 + i * 16 + l15;
        int ch = (ks * 4 + l4) ^ (row & 7);
        av[i] = *(const bf16x8*)((const char*)sA + row * 128 + ch * 16);
      }
#pragma unroll
      for (int i = 0; i < 4; ++i) {
        int row = wc * 64 + i * 16 + l15;
        int ch = (ks * 4 + l4) ^ (row & 7);
        bv[i] = *(const bf16x8*)((const char*)sB + row * 128 + ch * 16);
      }
#pragma unroll
      for (int mi = 0; mi < 4; ++mi)
#pragma unroll
        for (int ni = 0; ni < 4; ++ni)
          acc[mi][ni] = __builtin_amdgcn_mfma_f32_16x16x32_bf16(av[mi], bv[ni], acc[mi][ni], 0, 0, 0);
    }
  }
  // epilogue: C/D layout col=lane&15, row=(lane>>4)*4+reg
#pragma unroll
  for (int mi = 0; mi < 4; ++mi)
#pragma unroll
    for (int r = 0; r < 4; ++r) {
      long row = m0 + wr * 64 + mi * 16 + l4 * 4 + r;
#pragma unroll
      for (int ni = 0; ni < 4; ++ni) {
        long col = n0 + wc * 64 + ni * 16 + l15;
        if constexpr (CF32)
          ((float*)Cp)[row * (long)N + col] = acc[mi][ni][r];
        else
          ((__hip_bfloat16*)Cp)[row * (long)N + col] = __float2bfloat16(acc[mi][ni][r]);
      }
    }
}

// ---------------------------------------------------------------------------
// Flash attention, ALiBi + causal, exp2 domain. qkv bf16 [B*T][3072],
// col = which*1024 + h*64 + d. Block = (b,h) x 64 q-rows; 4 waves x 16 rows.
// ALiBi row-term (-slope*q) cancels in softmax -> score~ = s~ + sl2*kv.
// Q pre-scaled by 0.125*log2e. Only the diagonal KV tile needs masking.
// Grid: x = b*16+h (fast), y = qtile reversed (heavy blocks first).
// ---------------------------------------------------------------------------
__global__ __launch_bounds__(256) void attn_fwd(const __hip_bfloat16* __restrict__ qkv,
                                                __hip_bfloat16* __restrict__ O) {
  constexpr int T = 2048;
  constexpr int LDQ = 3072;
  const int b = blockIdx.x >> 4;
  const int h = blockIdx.x & 15;
  const int q0 = (31 - (int)blockIdx.y) * 64;
  const int tid = threadIdx.x;
  const int lane = tid & 63;
  const int w = tid >> 6;
  const int l15 = lane & 15, l4 = lane >> 4;

  __shared__ short sK[64 * 64];      // [kv][d], XOR chunk-swizzled
  __shared__ short sVT[64 * 72];     // [d][kv], stride 72
  __shared__ short sP[4][16 * 72];   // per-wave P [qloc][kv], stride 72

  const float sl2 = exp2f(-0.5f * (float)(h + 1)) * 1.44269504f;  // slope*log2e
  const long base_bt = (long)b * T;

  // Q fragments, pre-scaled by scale*log2e = 0.125*1.4427
  bf16x8 qf[2];
#pragma unroll
  for (int ks = 0; ks < 2; ++ks) {
    long qrow = base_bt + q0 + w * 16 + l15;
    bf16x8 v = *(const bf16x8*)(qkv + qrow * LDQ + h * 64 + ks * 32 + l4 * 8);
#pragma unroll
    for (int j = 0; j < 8; ++j)
      v[j] = f32_to_bf16_bits(bf16_bits_to_f32(v[j]) * 0.18033688f);
    qf[ks] = v;
  }

  f32x4 oacc[4] = {};                 // [nd][r]
  float mrun[4], lrun[4];
#pragma unroll
  for (int r = 0; r < 4; ++r) { mrun[r] = -1e30f; lrun[r] = 0.f; }

  for (int kv0 = 0; kv0 <= q0; kv0 += 64) {
    const bool masked = (kv0 == q0);   // only the diagonal tile
    __syncthreads();
    // stage K [64][64] via global_load_lds, pre-swizzled source
#pragma unroll
    for (int c = 0; c < 2; ++c) {
      int ci = c * 256 + tid;
      int row = ci >> 3;
      int sc = (ci & 7) ^ (row & 7);
      load_lds16(qkv + (base_bt + kv0 + row) * LDQ + 1024 + h * 64 + sc * 8,
                 (char*)sK + c * 4096 + w * 1024);
    }
    // stage V^T [64][72]
#pragma unroll
    for (int i = 0; i < 2; ++i) {
      int d0 = 8 * (w + 4 * i);
      bf16x8 v = *(const bf16x8*)(qkv + (base_bt + kv0 + lane) * LDQ + 2048 + h * 64 + d0);
#pragma unroll
      for (int j = 0; j < 8; ++j)
        sVT[(d0 + j) * 72 + lane] = v[j];
    }
    __syncthreads();

    // S~ = (Q*qs) @ K^T : C-layout (qloc=(l>>4)*4+r, kv_col=nf*16+(l&15))
    f32x4 s[4] = {};
#pragma unroll
    for (int ks = 0; ks < 2; ++ks) {
      bf16x8 kf[4];
#pragma unroll
      for (int nf = 0; nf < 4; ++nf) {
        int row = nf * 16 + l15;
        int ch = (ks * 4 + l4) ^ (row & 7);
        kf[nf] = *(const bf16x8*)((const char*)sK + row * 128 + ch * 16);
      }
#pragma unroll
      for (int nf = 0; nf < 4; ++nf)
        s[nf] = __builtin_amdgcn_mfma_f32_16x16x32_bf16(qf[ks], kf[nf], s[nf], 0, 0, 0);
    }

    // ALiBi column term (row term cancels in softmax)
    float al[4];
#pragma unroll
    for (int nf = 0; nf < 4; ++nf)
      al[nf] = sl2 * (float)(kv0 + nf * 16 + l15);

    // online softmax over 16-lane groups; 4 q-rows per lane (r)
#pragma unroll
    for (int r = 0; r < 4; ++r) {
      float sv[4];
#pragma unroll
      for (int nf = 0; nf < 4; ++nf)
        sv[nf] = s[nf][r] + al[nf];
      if (masked) {
        int qloc = w * 16 + l4 * 4 + r;
#pragma unroll
        for (int nf = 0; nf < 4; ++nf)
          sv[nf] = (nf * 16 + l15 <= qloc) ? sv[nf] : -1e30f;
      }
      float mx = fmaxf(fmaxf(sv[0], sv[1]), fmaxf(sv[2], sv[3]));
#pragma unroll
      for (int off = 1; off < 16; off <<= 1)
        mx = fmaxf(mx, __shfl_xor(mx, off, 64));
      float mnew = fmaxf(mrun[r], mx);
      float f = exp2f(mrun[r] - mnew);
      mrun[r] = mnew;
      float p[4], sum;
#pragma unroll
      for (int nf = 0; nf < 4; ++nf)
        p[nf] = exp2f(sv[nf] - mnew);
      sum = (p[0] + p[1]) + (p[2] + p[3]);
      int qloc = l4 * 4 + r;
#pragma unroll
      for (int nf = 0; nf < 4; ++nf)
        sP[w][qloc * 72 + nf * 16 + l15] = f32_to_bf16_bits(p[nf]);
#pragma unroll
      for (int off = 1; off < 16; off <<= 1)
        sum += __shfl_xor(sum, off, 64);
      lrun[r] = lrun[r] * f + sum;
#pragma unroll
      for (int nd = 0; nd < 4; ++nd)
        oacc[nd][r] *= f;
    }

    // fence per-wave sP writes before A-frag reads (rule 18)
    asm volatile("s_waitcnt lgkmcnt(0)" ::: "memory");
    __builtin_amdgcn_sched_barrier(0);

    // O += P @ V
#pragma unroll
    for (int ks = 0; ks < 2; ++ks) {
      bf16x8 pf = *(const bf16x8*)(sP[w] + l15 * 72 + ks * 32 + l4 * 8);
      bf16x8 vf[4];
#pragma unroll
      for (int nd = 0; nd < 4; ++nd)
        vf[nd] = *(const bf16x8*)(sVT + (nd * 16 + l15) * 72 + ks * 32 + l4 * 8);
#pragma unroll
      for (int nd = 0; nd < 4; ++nd)
        oacc[nd] = __builtin_amdgcn_mfma_f32_16x16x32_bf16(pf, vf[nd], oacc[nd], 0, 0, 0);
    }
  }

  // epilogue: O / l
#pragma unroll
  for (int r = 0; r < 4; ++r) {
    long q = base_bt + q0 + w * 16 + l4 * 4 + r;
    float inv = 1.0f / lrun[r];
#pragma unroll
    for (int nd = 0; nd < 4; ++nd) {
      int d = nd * 16 + l15;
      O[q * 1024 + h * 64 + d] = __float2bfloat16(oacc[nd][r] * inv);
    }
  }
}

extern "C" void kernel_launch(void* const* d_in, const int* in_sizes, int n_in,
                              void* d_out, int out_size, void* d_ws, size_t ws_size,
                              hipStream_t stream) {
  const float* x    = (const float*)d_in[0];   // [4096,1024] fp32
  const float* Wqkv = (const float*)d_in[1];   // [3072,1024] fp32
  const float* Wout = (const float*)d_in[2];   // [1024,1024] fp32
  float* out = (float*)d_out;                  // [4096,1024] fp32

  // ws layout (shorts): x_bf16 | Wqkv_bf16 | Wout_bf16 | qkv_ws ; attn aliases x_bf16
  short* xb  = (short*)d_ws;                         // 4096*1024
  short* wqb = xb + 4194304;                         // 3072*1024
  short* wob = wqb + 3145728;                        // 1024*1024
  short* qkv = wob + 1048576;                        // 4096*3072
  short* attn = xb;                                  // alias: x_bf16 dead after GEMM1

  dim3 blk(256);
  conv_f32_bf16<<<8192, blk, 0, stream>>>((const float4*)x, (const float4*)Wqkv,
                                          (const float4*)Wout, (short4v*)xb,
                                          (short4v*)wqb, (short4v*)wob);
  // qkv = x @ W_qkv^T : M=4096 N=3072 K=1024
  gemm_bt<false><<<dim3(24, 32), blk, 0, stream>>>((const __hip_bfloat16*)xb,
                                                   (const __hip_bfloat16*)wqb,
                                                   qkv, 4096, 3072, 1024);
  // attention: grid (bh=32 fast, qtile=32 reversed)
  attn_fwd<<<dim3(32, 32), blk, 0, stream>>>((const __hip_bfloat16*)qkv,
                                             (__hip_bfloat16*)attn);
  // out = attn @ W_out^T : M=4096 N=1024 K=1024 (fp32 out)
  gemm_bt<true><<<dim3(8, 32), blk, 0, stream>>>((const __hip_bfloat16*)attn,
                                                 (const __hip_bfloat16*)wob,
                                                 out, 4096, 1024, 1024);
}

// Round 8
// 188.399 us; speedup vs baseline: 1.5909x; 1.1300x over previous
//
#include <hip/hip_runtime.h>
#include <hip/hip_bf16.h>
#include <stdint.h>

typedef __attribute__((ext_vector_type(8))) short bf16x8;
typedef __attribute__((ext_vector_type(4))) short short4v;
typedef __attribute__((ext_vector_type(4))) float f32x4;

#define DEV static __device__ __forceinline__

DEV void load_lds16(const void* g, void* l) {
  __builtin_amdgcn_global_load_lds((const __attribute__((address_space(1))) char*)g,
                                   (__attribute__((address_space(3))) char*)l, 16, 0, 0);
}

DEV short f32_to_bf16_bits(float x) {
  union { __hip_bfloat16 h; short s; } u;
  u.h = __float2bfloat16(x);
  return u.s;
}
DEV float bf16_bits_to_f32(short s) {
  union { float f; unsigned u; } u;
  u.u = ((unsigned)(unsigned short)s) << 16;
  return u.f;
}

// DPP cross-lane (within 16-lane row): fmax with permuted value.
template<int CTRL>
DEV float dpp_fmax(float x) {
  union { float f; int i; } u, v;
  u.f = x;
  v.i = __builtin_amdgcn_update_dpp(0, u.i, CTRL, 0xf, 0xf, true);
  return fmaxf(x, v.f);
}
// full max over the 16-lane row, result in all 16 lanes
DEV float row16_max(float x) {
  x = dpp_fmax<0xB1>(x);    // quad_perm [1,0,3,2]  (xor 1)
  x = dpp_fmax<0x4E>(x);    // quad_perm [2,3,0,1]  (xor 2)
  x = dpp_fmax<0x124>(x);   // row_ror:4
  x = dpp_fmax<0x128>(x);   // row_ror:8
  return x;
}

// ---------------------------------------------------------------------------
// fp32 -> bf16 pre-convert for x, W_qkv, W_out (one dispatch, 3 segments).
// ---------------------------------------------------------------------------
#define NX4 1048576   // 4096*1024/4
#define NQ4 786432    // 3072*1024/4
#define NW4 262144    // 1024*1024/4
__global__ __launch_bounds__(256) void conv_f32_bf16(const float4* __restrict__ x,
                                                     const float4* __restrict__ wq,
                                                     const float4* __restrict__ wo,
                                                     short4v* __restrict__ ox,
                                                     short4v* __restrict__ oq,
                                                     short4v* __restrict__ ow) {
  int i = blockIdx.x * 256 + threadIdx.x;
  const float4* src; short4v* dst; int j;
  if (i < NX4)            { src = x;  dst = ox; j = i; }
  else if (i < NX4 + NQ4) { src = wq; dst = oq; j = i - NX4; }
  else                    { src = wo; dst = ow; j = i - NX4 - NQ4; }
  float4 v = src[j];
  short4v s;
  s[0] = f32_to_bf16_bits(v.x); s[1] = f32_to_bf16_bits(v.y);
  s[2] = f32_to_bf16_bits(v.z); s[3] = f32_to_bf16_bits(v.w);
  dst[j] = s;
}

// ---------------------------------------------------------------------------
// C[M,N] = A[M,K] @ Bt[N,K]^T, bf16 in. 128x128 tile, BK=64, 4 waves (2x2).
// global_load_lds width 16, XOR chunk swizzle (involution on both sides).
// ---------------------------------------------------------------------------
template<bool CF32>
__global__ __launch_bounds__(256) void gemm_bt(const __hip_bfloat16* __restrict__ A,
                                               const __hip_bfloat16* __restrict__ Bt,
                                               void* __restrict__ Cp,
                                               int M, int N, int K) {
  __shared__ short sA[128 * 64];
  __shared__ short sB[128 * 64];
  const int tid = threadIdx.x;
  const int lane = tid & 63;
  const int w = tid >> 6;
  const int wr = w >> 1, wc = w & 1;
  const int l15 = lane & 15, l4 = lane >> 4;
  const long m0 = (long)blockIdx.y * 128, n0 = (long)blockIdx.x * 128;

  f32x4 acc[4][4] = {};

  for (int k0 = 0; k0 < K; k0 += 64) {
    __syncthreads();
#pragma unroll
    for (int c = 0; c < 4; ++c) {
      int ci = c * 256 + tid;
      int row = ci >> 3;
      int sc = (ci & 7) ^ (row & 7);
      load_lds16(A + (m0 + row) * (long)K + k0 + sc * 8, (char*)sA + c * 4096 + w * 1024);
    }
#pragma unroll
    for (int c = 0; c < 4; ++c) {
      int ci = c * 256 + tid;
      int row = ci >> 3;
      int sc = (ci & 7) ^ (row & 7);
      load_lds16(Bt + (n0 + row) * (long)K + k0 + sc * 8, (char*)sB + c * 4096 + w * 1024);
    }
    __syncthreads();
#pragma unroll
    for (int ks = 0; ks < 2; ++ks) {
      bf16x8 av[4], bv[4];
#pragma unroll
      for (int i = 0; i < 4; ++i) {
        int row = wr * 64 + i * 16 + l15;
        int ch = (ks * 4 + l4) ^ (row & 7);
        av[i] = *(const bf16x8*)((const char*)sA + row * 128 + ch * 16);
      }
#pragma unroll
      for (int i = 0; i < 4; ++i) {
        int row = wc * 64 + i * 16 + l15;
        int ch = (ks * 4 + l4) ^ (row & 7);
        bv[i] = *(const bf16x8*)((const char*)sB + row * 128 + ch * 16);
      }
#pragma unroll
      for (int mi = 0; mi < 4; ++mi)
#pragma unroll
        for (int ni = 0; ni < 4; ++ni)
          acc[mi][ni] = __builtin_amdgcn_mfma_f32_16x16x32_bf16(av[mi], bv[ni], acc[mi][ni], 0, 0, 0);
    }
  }
#pragma unroll
  for (int mi = 0; mi < 4; ++mi)
#pragma unroll
    for (int r = 0; r < 4; ++r) {
      long row = m0 + wr * 64 + mi * 16 + l4 * 4 + r;
#pragma unroll
      for (int ni = 0; ni < 4; ++ni) {
        long col = n0 + wc * 64 + ni * 16 + l15;
        if constexpr (CF32)
          ((float*)Cp)[row * (long)N + col] = acc[mi][ni][r];
        else
          ((__hip_bfloat16*)Cp)[row * (long)N + col] = __float2bfloat16(acc[mi][ni][r]);
      }
    }
}

// ---------------------------------------------------------------------------
// Same GEMM with BM=64 (grid 2x blocks) for the small-N out-projection:
// 4 waves side-by-side over N (each 64x32), acc[4][2]. fp32 C out.
// ---------------------------------------------------------------------------
__global__ __launch_bounds__(256) void gemm_bt64(const __hip_bfloat16* __restrict__ A,
                                                 const __hip_bfloat16* __restrict__ Bt,
                                                 float* __restrict__ C,
                                                 int M, int N, int K) {
  __shared__ short sA[64 * 64];
  __shared__ short sB[128 * 64];
  const int tid = threadIdx.x;
  const int lane = tid & 63;
  const int w = tid >> 6;
  const int l15 = lane & 15, l4 = lane >> 4;
  const long m0 = (long)blockIdx.y * 64, n0 = (long)blockIdx.x * 128;

  f32x4 acc[4][2] = {};

  for (int k0 = 0; k0 < K; k0 += 64) {
    __syncthreads();
#pragma unroll
    for (int c = 0; c < 2; ++c) {
      int ci = c * 256 + tid;
      int row = ci >> 3;
      int sc = (ci & 7) ^ (row & 7);
      load_lds16(A + (m0 + row) * (long)K + k0 + sc * 8, (char*)sA + c * 4096 + w * 1024);
    }
#pragma unroll
    for (int c = 0; c < 4; ++c) {
      int ci = c * 256 + tid;
      int row = ci >> 3;
      int sc = (ci & 7) ^ (row & 7);
      load_lds16(Bt + (n0 + row) * (long)K + k0 + sc * 8, (char*)sB + c * 4096 + w * 1024);
    }
    __syncthreads();
#pragma unroll
    for (int ks = 0; ks < 2; ++ks) {
      bf16x8 av[4], bv[2];
#pragma unroll
      for (int i = 0; i < 4; ++i) {
        int row = i * 16 + l15;
        int ch = (ks * 4 + l4) ^ (row & 7);
        av[i] = *(const bf16x8*)((const char*)sA + row * 128 + ch * 16);
      }
#pragma unroll
      for (int i = 0; i < 2; ++i) {
        int row = w * 32 + i * 16 + l15;
        int ch = (ks * 4 + l4) ^ (row & 7);
        bv[i] = *(const bf16x8*)((const char*)sB + row * 128 + ch * 16);
      }
#pragma unroll
      for (int mi = 0; mi < 4; ++mi)
#pragma unroll
        for (int ni = 0; ni < 2; ++ni)
          acc[mi][ni] = __builtin_amdgcn_mfma_f32_16x16x32_bf16(av[mi], bv[ni], acc[mi][ni], 0, 0, 0);
    }
  }
#pragma unroll
  for (int mi = 0; mi < 4; ++mi)
#pragma unroll
    for (int r = 0; r < 4; ++r) {
      long row = m0 + mi * 16 + l4 * 4 + r;
#pragma unroll
      for (int ni = 0; ni < 2; ++ni) {
        long col = n0 + w * 32 + ni * 16 + l15;
        C[row * (long)N + col] = acc[mi][ni][r];
      }
    }
}

// ---------------------------------------------------------------------------
// Flash attention, ALiBi + causal, exp2 domain. Backward KV iteration from
// the diagonal: ALiBi column term (+sl2*kv) makes the running max start at
// its ceiling -> rescale (f!=1) is rare; skipped exactly when no row grows.
// Row-sum of P comes free from PV via a ones-fragment MFMA (5th accumulator).
// Row max uses DPP (quad_perm/row_ror) -- no LDS shuffles in softmax.
// ---------------------------------------------------------------------------
__global__ __launch_bounds__(256) void attn_fwd(const __hip_bfloat16* __restrict__ qkv,
                                                __hip_bfloat16* __restrict__ O) {
  constexpr int T = 2048;
  constexpr int LDQ = 3072;
  const int b = blockIdx.x >> 4;
  const int h = blockIdx.x & 15;
  const int q0 = (31 - (int)blockIdx.y) * 64;
  const int tid = threadIdx.x;
  const int lane = tid & 63;
  const int w = tid >> 6;
  const int l15 = lane & 15, l4 = lane >> 4;

  __shared__ short sK[64 * 64];      // [kv][d], XOR chunk-swizzled
  __shared__ short sVT[64 * 72];     // [d][kv], stride 72
  __shared__ short sP[4][16 * 72];   // per-wave P [qloc][kv], stride 72

  const float sl2 = exp2f(-0.5f * (float)(h + 1)) * 1.44269504f;  // slope*log2e
  const long base_bt = (long)b * T;

  // Q fragments, pre-scaled by scale*log2e = 0.125*1.4427
  bf16x8 qf[2];
#pragma unroll
  for (int ks = 0; ks < 2; ++ks) {
    long qrow = base_bt + q0 + w * 16 + l15;
    bf16x8 v = *(const bf16x8*)(qkv + qrow * LDQ + h * 64 + ks * 32 + l4 * 8);
#pragma unroll
    for (int j = 0; j < 8; ++j)
      v[j] = f32_to_bf16_bits(bf16_bits_to_f32(v[j]) * 0.18033688f);
    qf[ks] = v;
  }

  bf16x8 ones;
#pragma unroll
  for (int j = 0; j < 8; ++j) ones[j] = (short)0x3F80;  // bf16 1.0

  f32x4 oacc[4] = {};                 // [nd][r]
  f32x4 lacc = {};                    // row-sum accumulator (P @ ones)
  float mrun[4];
#pragma unroll
  for (int r = 0; r < 4; ++r) mrun[r] = -1e30f;

  for (int kv0 = q0; kv0 >= 0; kv0 -= 64) {
    const bool masked = (kv0 == q0);   // only the diagonal tile
    __syncthreads();
    // stage K [64][64] via global_load_lds, pre-swizzled source
#pragma unroll
    for (int c = 0; c < 2; ++c) {
      int ci = c * 256 + tid;
      int row = ci >> 3;
      int sc = (ci & 7) ^ (row & 7);
      load_lds16(qkv + (base_bt + kv0 + row) * LDQ + 1024 + h * 64 + sc * 8,
                 (char*)sK + c * 4096 + w * 1024);
    }
    // stage V^T [64][72]
#pragma unroll
    for (int i = 0; i < 2; ++i) {
      int d0 = 8 * (w + 4 * i);
      bf16x8 v = *(const bf16x8*)(qkv + (base_bt + kv0 + lane) * LDQ + 2048 + h * 64 + d0);
#pragma unroll
      for (int j = 0; j < 8; ++j)
        sVT[(d0 + j) * 72 + lane] = v[j];
    }
    __syncthreads();

    // S~ = (Q*qs) @ K^T : C-layout (qloc=(l>>4)*4+r, kv_col=nf*16+(l&15))
    f32x4 s[4] = {};
#pragma unroll
    for (int ks = 0; ks < 2; ++ks) {
      bf16x8 kf[4];
#pragma unroll
      for (int nf = 0; nf < 4; ++nf) {
        int row = nf * 16 + l15;
        int ch = (ks * 4 + l4) ^ (row & 7);
        kf[nf] = *(const bf16x8*)((const char*)sK + row * 128 + ch * 16);
      }
#pragma unroll
      for (int nf = 0; nf < 4; ++nf)
        s[nf] = __builtin_amdgcn_mfma_f32_16x16x32_bf16(qf[ks], kf[nf], s[nf], 0, 0, 0);
    }

    // alibi + mask in place, then DPP row-max
    float mx[4];
#pragma unroll
    for (int r = 0; r < 4; ++r) {
#pragma unroll
      for (int nf = 0; nf < 4; ++nf) {
        float val = s[nf][r] + sl2 * (float)(kv0 + nf * 16 + l15);
        if (masked) {
          int qloc = w * 16 + l4 * 4 + r;
          val = (nf * 16 + l15 <= qloc) ? val : -1e30f;
        }
        s[nf][r] = val;
      }
      float m4 = fmaxf(fmaxf(s[0][r], s[1][r]), fmaxf(s[2][r], s[3][r]));
      mx[r] = row16_max(m4);
    }

    // exact defer-max: rescale only if some row's max grew (rare going backward)
    bool grow = (mx[0] > mrun[0]) | (mx[1] > mrun[1]) |
                (mx[2] > mrun[2]) | (mx[3] > mrun[3]);
    if (__any(grow ? 1 : 0)) {
#pragma unroll
      for (int r = 0; r < 4; ++r) {
        float mnew = fmaxf(mrun[r], mx[r]);
        float f = exp2f(mrun[r] - mnew);
        mrun[r] = mnew;
        lacc[r] *= f;
#pragma unroll
        for (int nd = 0; nd < 4; ++nd)
          oacc[nd][r] *= f;
      }
    }

    // P = exp2(s - mrun), to per-wave LDS
#pragma unroll
    for (int r = 0; r < 4; ++r) {
      int qloc = l4 * 4 + r;
#pragma unroll
      for (int nf = 0; nf < 4; ++nf) {
        float p = exp2f(s[nf][r] - mrun[r]);
        sP[w][qloc * 72 + nf * 16 + l15] = f32_to_bf16_bits(p);
      }
    }

    // fence per-wave sP writes before A-frag reads (rule 18)
    asm volatile("s_waitcnt lgkmcnt(0)" ::: "memory");
    __builtin_amdgcn_sched_barrier(0);

    // O += P @ V ; row-sum rides along as P @ ones
#pragma unroll
    for (int ks = 0; ks < 2; ++ks) {
      bf16x8 pf = *(const bf16x8*)(sP[w] + l15 * 72 + ks * 32 + l4 * 8);
      lacc = __builtin_amdgcn_mfma_f32_16x16x32_bf16(pf, ones, lacc, 0, 0, 0);
      bf16x8 vf[4];
#pragma unroll
      for (int nd = 0; nd < 4; ++nd)
        vf[nd] = *(const bf16x8*)(sVT + (nd * 16 + l15) * 72 + ks * 32 + l4 * 8);
#pragma unroll
      for (int nd = 0; nd < 4; ++nd)
        oacc[nd] = __builtin_amdgcn_mfma_f32_16x16x32_bf16(pf, vf[nd], oacc[nd], 0, 0, 0);
    }
  }

  // epilogue: O / rowsum
#pragma unroll
  for (int r = 0; r < 4; ++r) {
    long q = base_bt + q0 + w * 16 + l4 * 4 + r;
    float inv = 1.0f / lacc[r];
#pragma unroll
    for (int nd = 0; nd < 4; ++nd) {
      int d = nd * 16 + l15;
      O[q * 1024 + h * 64 + d] = __float2bfloat16(oacc[nd][r] * inv);
    }
  }
}

extern "C" void kernel_launch(void* const* d_in, const int* in_sizes, int n_in,
                              void* d_out, int out_size, void* d_ws, size_t ws_size,
                              hipStream_t stream) {
  const float* x    = (const float*)d_in[0];   // [4096,1024] fp32
  const float* Wqkv = (const float*)d_in[1];   // [3072,1024] fp32
  const float* Wout = (const float*)d_in[2];   // [1024,1024] fp32
  float* out = (float*)d_out;                  // [4096,1024] fp32

  // ws layout (shorts): x_bf16 | Wqkv_bf16 | Wout_bf16 | qkv_ws ; attn aliases x_bf16
  short* xb  = (short*)d_ws;                         // 4096*1024
  short* wqb = xb + 4194304;                         // 3072*1024
  short* wob = wqb + 3145728;                        // 1024*1024
  short* qkv = wob + 1048576;                        // 4096*3072
  short* attn = xb;                                  // alias: x_bf16 dead after GEMM1

  dim3 blk(256);
  conv_f32_bf16<<<8192, blk, 0, stream>>>((const float4*)x, (const float4*)Wqkv,
                                          (const float4*)Wout, (short4v*)xb,
                                          (short4v*)wqb, (short4v*)wob);
  // qkv = x @ W_qkv^T : M=4096 N=3072 K=1024
  gemm_bt<false><<<dim3(24, 32), blk, 0, stream>>>((const __hip_bfloat16*)xb,
                                                   (const __hip_bfloat16*)wqb,
                                                   qkv, 4096, 3072, 1024);
  // attention: grid (bh=32 fast, qtile=32 reversed)
  attn_fwd<<<dim3(32, 32), blk, 0, stream>>>((const __hip_bfloat16*)qkv,
                                             (__hip_bfloat16*)attn);
  // out = attn @ W_out^T : M=4096 N=1024 K=1024 (fp32 out), BM=64 tile
  gemm_bt64<<<dim3(8, 64), blk, 0, stream>>>((const __hip_bfloat16*)attn,
                                             (const __hip_bfloat16*)wob,
                                             out, 4096, 1024, 1024);
}

// Round 10
// 186.614 us; speedup vs baseline: 1.6061x; 1.0096x over previous
//
#include <hip/hip_runtime.h>
#include <hip/hip_bf16.h>
#include <stdint.h>

typedef __attribute__((ext_vector_type(8))) short bf16x8;
typedef __attribute__((ext_vector_type(4))) short short4v;
typedef __attribute__((ext_vector_type(4))) float f32x4;

#define DEV static __device__ __forceinline__

DEV void load_lds16(const void* g, void* l) {
  __builtin_amdgcn_global_load_lds((const __attribute__((address_space(1))) char*)g,
                                   (__attribute__((address_space(3))) char*)l, 16, 0, 0);
}

DEV short f32_to_bf16_bits(float x) {
  union { __hip_bfloat16 h; short s; } u;
  u.h = __float2bfloat16(x);
  return u.s;
}
DEV float bf16_bits_to_f32(short s) {
  union { float f; unsigned u; } u;
  u.u = ((unsigned)(unsigned short)s) << 16;
  return u.f;
}

// DPP cross-lane (within 16-lane row): fmax with permuted value.
template<int CTRL>
DEV float dpp_fmax(float x) {
  union { float f; int i; } u, v;
  u.f = x;
  v.i = __builtin_amdgcn_update_dpp(0, u.i, CTRL, 0xf, 0xf, true);
  return fmaxf(x, v.f);
}
// full max over the 16-lane row, result in all 16 lanes
DEV float row16_max(float x) {
  x = dpp_fmax<0xB1>(x);    // quad_perm [1,0,3,2]  (xor 1)
  x = dpp_fmax<0x4E>(x);    // quad_perm [2,3,0,1]  (xor 2)
  x = dpp_fmax<0x124>(x);   // row_ror:4
  x = dpp_fmax<0x128>(x);   // row_ror:8
  return x;
}

// ---------------------------------------------------------------------------
// fp32 -> bf16 pre-convert for x, W_qkv, W_out (one dispatch, 3 segments).
// ---------------------------------------------------------------------------
#define NX4 1048576   // 4096*1024/4
#define NQ4 786432    // 3072*1024/4
#define NW4 262144    // 1024*1024/4
__global__ __launch_bounds__(256) void conv_f32_bf16(const float4* __restrict__ x,
                                                     const float4* __restrict__ wq,
                                                     const float4* __restrict__ wo,
                                                     short4v* __restrict__ ox,
                                                     short4v* __restrict__ oq,
                                                     short4v* __restrict__ ow) {
  int i = blockIdx.x * 256 + threadIdx.x;
  const float4* src; short4v* dst; int j;
  if (i < NX4)            { src = x;  dst = ox; j = i; }
  else if (i < NX4 + NQ4) { src = wq; dst = oq; j = i - NX4; }
  else                    { src = wo; dst = ow; j = i - NX4 - NQ4; }
  float4 v = src[j];
  short4v s;
  s[0] = f32_to_bf16_bits(v.x); s[1] = f32_to_bf16_bits(v.y);
  s[2] = f32_to_bf16_bits(v.z); s[3] = f32_to_bf16_bits(v.w);
  dst[j] = s;
}

// ---------------------------------------------------------------------------
// C[M,N] = A[M,K] @ Bt[N,K]^T, bf16 in. 128x128 tile, BK=64, 4 waves (2x2).
// global_load_lds width 16, XOR chunk swizzle (involution on both sides).
// ---------------------------------------------------------------------------
template<bool CF32>
__global__ __launch_bounds__(256) void gemm_bt(const __hip_bfloat16* __restrict__ A,
                                               const __hip_bfloat16* __restrict__ Bt,
                                               void* __restrict__ Cp,
                                               int M, int N, int K) {
  __shared__ short sA[128 * 64];
  __shared__ short sB[128 * 64];
  const int tid = threadIdx.x;
  const int lane = tid & 63;
  const int w = tid >> 6;
  const int wr = w >> 1, wc = w & 1;
  const int l15 = lane & 15, l4 = lane >> 4;
  const long m0 = (long)blockIdx.y * 128, n0 = (long)blockIdx.x * 128;

  f32x4 acc[4][4] = {};

  for (int k0 = 0; k0 < K; k0 += 64) {
    __syncthreads();
#pragma unroll
    for (int c = 0; c < 4; ++c) {
      int ci = c * 256 + tid;
      int row = ci >> 3;
      int sc = (ci & 7) ^ (row & 7);
      load_lds16(A + (m0 + row) * (long)K + k0 + sc * 8, (char*)sA + c * 4096 + w * 1024);
    }
#pragma unroll
    for (int c = 0; c < 4; ++c) {
      int ci = c * 256 + tid;
      int row = ci >> 3;
      int sc = (ci & 7) ^ (row & 7);
      load_lds16(Bt + (n0 + row) * (long)K + k0 + sc * 8, (char*)sB + c * 4096 + w * 1024);
    }
    __syncthreads();
#pragma unroll
    for (int ks = 0; ks < 2; ++ks) {
      bf16x8 av[4], bv[4];
#pragma unroll
      for (int i = 0; i < 4; ++i) {
        int row = wr * 64 + i * 16 + l15;
        int ch = (ks * 4 + l4) ^ (row & 7);
        av[i] = *(const bf16x8*)((const char*)sA + row * 128 + ch * 16);
      }
#pragma unroll
      for (int i = 0; i < 4; ++i) {
        int row = wc * 64 + i * 16 + l15;
        int ch = (ks * 4 + l4) ^ (row & 7);
        bv[i] = *(const bf16x8*)((const char*)sB + row * 128 + ch * 16);
      }
#pragma unroll
      for (int mi = 0; mi < 4; ++mi)
#pragma unroll
        for (int ni = 0; ni < 4; ++ni)
          acc[mi][ni] = __builtin_amdgcn_mfma_f32_16x16x32_bf16(av[mi], bv[ni], acc[mi][ni], 0, 0, 0);
    }
  }
#pragma unroll
  for (int mi = 0; mi < 4; ++mi)
#pragma unroll
    for (int r = 0; r < 4; ++r) {
      long row = m0 + wr * 64 + mi * 16 + l4 * 4 + r;
#pragma unroll
      for (int ni = 0; ni < 4; ++ni) {
        long col = n0 + wc * 64 + ni * 16 + l15;
        if constexpr (CF32)
          ((float*)Cp)[row * (long)N + col] = acc[mi][ni][r];
        else
          ((__hip_bfloat16*)Cp)[row * (long)N + col] = __float2bfloat16(acc[mi][ni][r]);
      }
    }
}

// ---------------------------------------------------------------------------
// Same GEMM with BM=64 (grid 2x blocks) for the small-N out-projection:
// 4 waves side-by-side over N (each 64x32), acc[4][2]. fp32 C out.
// ---------------------------------------------------------------------------
__global__ __launch_bounds__(256) void gemm_bt64(const __hip_bfloat16* __restrict__ A,
                                                 const __hip_bfloat16* __restrict__ Bt,
                                                 float* __restrict__ C,
                                                 int M, int N, int K) {
  __shared__ short sA[64 * 64];
  __shared__ short sB[128 * 64];
  const int tid = threadIdx.x;
  const int lane = tid & 63;
  const int w = tid >> 6;
  const int l15 = lane & 15, l4 = lane >> 4;
  const long m0 = (long)blockIdx.y * 64, n0 = (long)blockIdx.x * 128;

  f32x4 acc[4][2] = {};

  for (int k0 = 0; k0 < K; k0 += 64) {
    __syncthreads();
#pragma unroll
    for (int c = 0; c < 2; ++c) {
      int ci = c * 256 + tid;
      int row = ci >> 3;
      int sc = (ci & 7) ^ (row & 7);
      load_lds16(A + (m0 + row) * (long)K + k0 + sc * 8, (char*)sA + c * 4096 + w * 1024);
    }
#pragma unroll
    for (int c = 0; c < 4; ++c) {
      int ci = c * 256 + tid;
      int row = ci >> 3;
      int sc = (ci & 7) ^ (row & 7);
      load_lds16(Bt + (n0 + row) * (long)K + k0 + sc * 8, (char*)sB + c * 4096 + w * 1024);
    }
    __syncthreads();
#pragma unroll
    for (int ks = 0; ks < 2; ++ks) {
      bf16x8 av[4], bv[2];
#pragma unroll
      for (int i = 0; i < 4; ++i) {
        int row = i * 16 + l15;
        int ch = (ks * 4 + l4) ^ (row & 7);
        av[i] = *(const bf16x8*)((const char*)sA + row * 128 + ch * 16);
      }
#pragma unroll
      for (int i = 0; i < 2; ++i) {
        int row = w * 32 + i * 16 + l15;
        int ch = (ks * 4 + l4) ^ (row & 7);
        bv[i] = *(const bf16x8*)((const char*)sB + row * 128 + ch * 16);
      }
#pragma unroll
      for (int mi = 0; mi < 4; ++mi)
#pragma unroll
        for (int ni = 0; ni < 2; ++ni)
          acc[mi][ni] = __builtin_amdgcn_mfma_f32_16x16x32_bf16(av[mi], bv[ni], acc[mi][ni], 0, 0, 0);
    }
  }
#pragma unroll
  for (int mi = 0; mi < 4; ++mi)
#pragma unroll
    for (int r = 0; r < 4; ++r) {
      long row = m0 + mi * 16 + l4 * 4 + r;
#pragma unroll
      for (int ni = 0; ni < 2; ++ni) {
        long col = n0 + w * 32 + ni * 16 + l15;
        C[row * (long)N + col] = acc[mi][ni][r];
      }
    }
}

// ---------------------------------------------------------------------------
// Flash attention, ALiBi + causal, exp2 domain, backward KV iteration.
// 1-deep pipeline (dbuf sK/sVT; K gload_lds + V reg-loads issued right
// after the tile barrier, V written to LDS after compute — T14); ALiBi
// column term folded into the QK MFMA C-init; defer-max threshold 8
// (exact: P bounded by 2^8). Row-sum via P@ones MFMA; DPP row-max.
// ---------------------------------------------------------------------------
__global__ __launch_bounds__(256) void attn_fwd(const __hip_bfloat16* __restrict__ qkv,
                                                __hip_bfloat16* __restrict__ O) {
  constexpr int T = 2048;
  constexpr int LDQ = 3072;
  const int b = blockIdx.x >> 4;
  const int h = blockIdx.x & 15;
  const int q0 = (31 - (int)blockIdx.y) * 64;
  const int tid = threadIdx.x;
  const int lane = tid & 63;
  const int w = tid >> 6;
  const int l15 = lane & 15, l4 = lane >> 4;

  __shared__ short sK[2][64 * 64];   // [kv][d], XOR chunk-swizzled, dbuf
  __shared__ short sVT[2][64 * 72];  // [d][kv], stride 72, dbuf
  __shared__ short sP[4][16 * 72];   // per-wave P [qloc][kv], stride 72

  const float sl2 = exp2f(-0.5f * (float)(h + 1)) * 1.44269504f;  // slope*log2e
  const long base_bt = (long)b * T;

  const __hip_bfloat16* Kbase = qkv + base_bt * LDQ + 1024 + h * 64;
  const __hip_bfloat16* Vbase = qkv + base_bt * LDQ + 2048 + h * 64;

  // loop-invariant staging offsets
  long koff[2];  size_t kdst_off[2];
#pragma unroll
  for (int c = 0; c < 2; ++c) {
    int ci = c * 256 + tid;
    int row = ci >> 3;
    int sc = (ci & 7) ^ (row & 7);
    koff[c] = (long)row * LDQ + sc * 8;
    kdst_off[c] = (size_t)(c * 4096 + w * 1024);
  }
  long voff[2];
#pragma unroll
  for (int i = 0; i < 2; ++i)
    voff[i] = (long)lane * LDQ + 8 * (w + 4 * i);

  // Q fragments, pre-scaled by scale*log2e = 0.125*1.4427
  bf16x8 qf[2];
#pragma unroll
  for (int ks = 0; ks < 2; ++ks) {
    long qrow = base_bt + q0 + w * 16 + l15;
    bf16x8 v = *(const bf16x8*)(qkv + qrow * LDQ + h * 64 + ks * 32 + l4 * 8);
#pragma unroll
    for (int j = 0; j < 8; ++j)
      v[j] = f32_to_bf16_bits(bf16_bits_to_f32(v[j]) * 0.18033688f);
    qf[ks] = v;
  }

  bf16x8 ones;
#pragma unroll
  for (int j = 0; j < 8; ++j) ones[j] = (short)0x3F80;  // bf16 1.0

  f32x4 oacc[4] = {};                 // [nd][r]
  f32x4 lacc = {};                    // row-sum accumulator (P @ ones)
  float mrun[4];
#pragma unroll
  for (int r = 0; r < 4; ++r) mrun[r] = -1e30f;

  // ---- prologue: stage tile kv0=q0 into buf 0 ----
  bf16x8 vreg[2];
  {
    const __hip_bfloat16* Kt = Kbase + (long)q0 * LDQ;
    const __hip_bfloat16* Vt = Vbase + (long)q0 * LDQ;
#pragma unroll
    for (int c = 0; c < 2; ++c)
      load_lds16(Kt + koff[c], (char*)sK[0] + kdst_off[c]);
#pragma unroll
    for (int i = 0; i < 2; ++i)
      vreg[i] = *(const bf16x8*)(Vt + voff[i]);
    asm volatile("s_waitcnt vmcnt(0)" ::: "memory");
#pragma unroll
    for (int i = 0; i < 2; ++i) {
      int d0 = 8 * (w + 4 * i);
#pragma unroll
      for (int j = 0; j < 8; ++j)
        sVT[0][(d0 + j) * 72 + lane] = vreg[i][j];
    }
  }

  int cur = 0;
  for (int kv0 = q0; kv0 >= 0; kv0 -= 64) {
    const bool masked = (kv0 == q0);    // only the diagonal tile
    const bool have_next = (kv0 > 0);
    __syncthreads();                    // buf[cur] K + V^T visible

    // issue next-tile staging immediately (hidden under compute)
    if (have_next) {
      const __hip_bfloat16* Kt = Kbase + (long)(kv0 - 64) * LDQ;
      const __hip_bfloat16* Vt = Vbase + (long)(kv0 - 64) * LDQ;
#pragma unroll
      for (int c = 0; c < 2; ++c)
        load_lds16(Kt + koff[c], (char*)sK[cur ^ 1] + kdst_off[c]);
#pragma unroll
      for (int i = 0; i < 2; ++i)
        vreg[i] = *(const bf16x8*)(Vt + voff[i]);
    }

    // S~ = (Q*qs) @ K^T + alibi (C-init): C-layout (qloc=(l>>4)*4+r, kv=nf*16+l15)
    f32x4 s[4];
#pragma unroll
    for (int nf = 0; nf < 4; ++nf) {
      float al = sl2 * (float)(kv0 + nf * 16 + l15);
      s[nf] = f32x4{al, al, al, al};
    }
#pragma unroll
    for (int ks = 0; ks < 2; ++ks) {
      bf16x8 kf[4];
#pragma unroll
      for (int nf = 0; nf < 4; ++nf) {
        int row = nf * 16 + l15;
        int ch = (ks * 4 + l4) ^ (row & 7);
        kf[nf] = *(const bf16x8*)((const char*)sK[cur] + row * 128 + ch * 16);
      }
#pragma unroll
      for (int nf = 0; nf < 4; ++nf)
        s[nf] = __builtin_amdgcn_mfma_f32_16x16x32_bf16(qf[ks], kf[nf], s[nf], 0, 0, 0);
    }

    // mask (diag tile only) + DPP row-max
    float mx[4];
#pragma unroll
    for (int r = 0; r < 4; ++r) {
      if (masked) {
        int qloc = w * 16 + l4 * 4 + r;
#pragma unroll
        for (int nf = 0; nf < 4; ++nf)
          s[nf][r] = (nf * 16 + l15 <= qloc) ? s[nf][r] : -1e30f;
      }
      float m4 = fmaxf(fmaxf(s[0][r], s[1][r]), fmaxf(s[2][r], s[3][r]));
      mx[r] = row16_max(m4);
    }

    // defer-max, threshold 8 (exact: P <= 2^8)
    bool grow = (mx[0] > mrun[0] + 8.f) | (mx[1] > mrun[1] + 8.f) |
                (mx[2] > mrun[2] + 8.f) | (mx[3] > mrun[3] + 8.f);
    if (__any(grow ? 1 : 0)) {
#pragma unroll
      for (int r = 0; r < 4; ++r) {
        float mnew = fmaxf(mrun[r], mx[r]);
        float f = exp2f(mrun[r] - mnew);
        mrun[r] = mnew;
        lacc[r] *= f;
#pragma unroll
        for (int nd = 0; nd < 4; ++nd)
          oacc[nd][r] *= f;
      }
    }

    // P = exp2(s - mrun), to per-wave LDS
#pragma unroll
    for (int r = 0; r < 4; ++r) {
      int qloc = l4 * 4 + r;
#pragma unroll
      for (int nf = 0; nf < 4; ++nf) {
        float p = exp2f(s[nf][r] - mrun[r]);
        sP[w][qloc * 72 + nf * 16 + l15] = f32_to_bf16_bits(p);
      }
    }

    // fence per-wave sP writes before A-frag reads (rule 18)
    asm volatile("s_waitcnt lgkmcnt(0)" ::: "memory");
    __builtin_amdgcn_sched_barrier(0);

    // O += P @ V ; row-sum rides along as P @ ones
#pragma unroll
    for (int ks = 0; ks < 2; ++ks) {
      bf16x8 pf = *(const bf16x8*)(sP[w] + l15 * 72 + ks * 32 + l4 * 8);
      lacc = __builtin_amdgcn_mfma_f32_16x16x32_bf16(pf, ones, lacc, 0, 0, 0);
      bf16x8 vf[4];
#pragma unroll
      for (int nd = 0; nd < 4; ++nd)
        vf[nd] = *(const bf16x8*)(sVT[cur] + (nd * 16 + l15) * 72 + ks * 32 + l4 * 8);
#pragma unroll
      for (int nd = 0; nd < 4; ++nd)
        oacc[nd] = __builtin_amdgcn_mfma_f32_16x16x32_bf16(pf, vf[nd], oacc[nd], 0, 0, 0);
    }

    // drain next-tile loads, write V^T into the other buffer
    if (have_next) {
      asm volatile("s_waitcnt vmcnt(0)" ::: "memory");
#pragma unroll
      for (int i = 0; i < 2; ++i) {
        int d0 = 8 * (w + 4 * i);
#pragma unroll
        for (int j = 0; j < 8; ++j)
          sVT[cur ^ 1][(d0 + j) * 72 + lane] = vreg[i][j];
      }
    }
    cur ^= 1;
  }

  // epilogue: O / rowsum
#pragma unroll
  for (int r = 0; r < 4; ++r) {
    long q = base_bt + q0 + w * 16 + l4 * 4 + r;
    float inv = 1.0f / lacc[r];
#pragma unroll
    for (int nd = 0; nd < 4; ++nd) {
      int d = nd * 16 + l15;
      O[q * 1024 + h * 64 + d] = __float2bfloat16(oacc[nd][r] * inv);
    }
  }
}

extern "C" void kernel_launch(void* const* d_in, const int* in_sizes, int n_in,
                              void* d_out, int out_size, void* d_ws, size_t ws_size,
                              hipStream_t stream) {
  const float* x    = (const float*)d_in[0];   // [4096,1024] fp32
  const float* Wqkv = (const float*)d_in[1];   // [3072,1024] fp32
  const float* Wout = (const float*)d_in[2];   // [1024,1024] fp32
  float* out = (float*)d_out;                  // [4096,1024] fp32

  // ws layout (shorts): x_bf16 | Wqkv_bf16 | Wout_bf16 | qkv_ws ; attn aliases x_bf16
  short* xb  = (short*)d_ws;                         // 4096*1024
  short* wqb = xb + 4194304;                         // 3072*1024
  short* wob = wqb + 3145728;                        // 1024*1024
  short* qkv = wob + 1048576;                        // 4096*3072
  short* attn = xb;                                  // alias: x_bf16 dead after GEMM1

  dim3 blk(256);
  conv_f32_bf16<<<8192, blk, 0, stream>>>((const float4*)x, (const float4*)Wqkv,
                                          (const float4*)Wout, (short4v*)xb,
                                          (short4v*)wqb, (short4v*)wob);
  // qkv = x @ W_qkv^T : M=4096 N=3072 K=1024
  gemm_bt<false><<<dim3(24, 32), blk, 0, stream>>>((const __hip_bfloat16*)xb,
                                                   (const __hip_bfloat16*)wqb,
                                                   qkv, 4096, 3072, 1024);
  // attention: grid (bh=32 fast, qtile=32 reversed)
  attn_fwd<<<dim3(32, 32), blk, 0, stream>>>((const __hip_bfloat16*)qkv,
                                             (__hip_bfloat16*)attn);
  // out = attn @ W_out^T : M=4096 N=1024 K=1024 (fp32 out), BM=64 tile
  gemm_bt64<<<dim3(8, 64), blk, 0, stream>>>((const __hip_bfloat16*)attn,
                                             (const __hip_bfloat16*)wob,
                                             out, 4096, 1024, 1024);
}

// Round 11
// 185.052 us; speedup vs baseline: 1.6197x; 1.0084x over previous
//
#include <hip/hip_runtime.h>
#include <hip/hip_bf16.h>
#include <stdint.h>

typedef __attribute__((ext_vector_type(8))) short bf16x8;
typedef __attribute__((ext_vector_type(4))) short short4v;
typedef __attribute__((ext_vector_type(4))) float f32x4;
typedef __attribute__((ext_vector_type(2))) unsigned int uint2v;

#define DEV static __device__ __forceinline__

DEV void load_lds16(const void* g, void* l) {
  __builtin_amdgcn_global_load_lds((const __attribute__((address_space(1))) char*)g,
                                   (__attribute__((address_space(3))) char*)l, 16, 0, 0);
}

DEV short f32_to_bf16_bits(float x) {
  union { __hip_bfloat16 h; short s; } u;
  u.h = __float2bfloat16(x);
  return u.s;
}
DEV float bf16_bits_to_f32(short s) {
  union { float f; unsigned u; } u;
  u.u = ((unsigned)(unsigned short)s) << 16;
  return u.f;
}

// ---------------------------------------------------------------------------
// fp32 -> bf16 pre-convert for x, W_qkv, W_out (one dispatch, 3 segments).
// ---------------------------------------------------------------------------
#define NX4 1048576   // 4096*1024/4
#define NQ4 786432    // 3072*1024/4
#define NW4 262144    // 1024*1024/4
__global__ __launch_bounds__(256) void conv_f32_bf16(const float4* __restrict__ x,
                                                     const float4* __restrict__ wq,
                                                     const float4* __restrict__ wo,
                                                     short4v* __restrict__ ox,
                                                     short4v* __restrict__ oq,
                                                     short4v* __restrict__ ow) {
  int i = blockIdx.x * 256 + threadIdx.x;
  const float4* src; short4v* dst; int j;
  if (i < NX4)            { src = x;  dst = ox; j = i; }
  else if (i < NX4 + NQ4) { src = wq; dst = oq; j = i - NX4; }
  else                    { src = wo; dst = ow; j = i - NX4 - NQ4; }
  float4 v = src[j];
  short4v s;
  s[0] = f32_to_bf16_bits(v.x); s[1] = f32_to_bf16_bits(v.y);
  s[2] = f32_to_bf16_bits(v.z); s[3] = f32_to_bf16_bits(v.w);
  dst[j] = s;
}

// ---------------------------------------------------------------------------
// C[M,N] = A[M,K] @ Bt[N,K]^T, bf16 in. 128x128 tile, BK=64, 4 waves (2x2).
// global_load_lds width 16, XOR chunk swizzle (involution on both sides).
// ---------------------------------------------------------------------------
template<bool CF32>
__global__ __launch_bounds__(256) void gemm_bt(const __hip_bfloat16* __restrict__ A,
                                               const __hip_bfloat16* __restrict__ Bt,
                                               void* __restrict__ Cp,
                                               int M, int N, int K) {
  __shared__ short sA[128 * 64];
  __shared__ short sB[128 * 64];
  const int tid = threadIdx.x;
  const int lane = tid & 63;
  const int w = tid >> 6;
  const int wr = w >> 1, wc = w & 1;
  const int l15 = lane & 15, l4 = lane >> 4;
  const long m0 = (long)blockIdx.y * 128, n0 = (long)blockIdx.x * 128;

  f32x4 acc[4][4] = {};

  for (int k0 = 0; k0 < K; k0 += 64) {
    __syncthreads();
#pragma unroll
    for (int c = 0; c < 4; ++c) {
      int ci = c * 256 + tid;
      int row = ci >> 3;
      int sc = (ci & 7) ^ (row & 7);
      load_lds16(A + (m0 + row) * (long)K + k0 + sc * 8, (char*)sA + c * 4096 + w * 1024);
    }
#pragma unroll
    for (int c = 0; c < 4; ++c) {
      int ci = c * 256 + tid;
      int row = ci >> 3;
      int sc = (ci & 7) ^ (row & 7);
      load_lds16(Bt + (n0 + row) * (long)K + k0 + sc * 8, (char*)sB + c * 4096 + w * 1024);
    }
    __syncthreads();
#pragma unroll
    for (int ks = 0; ks < 2; ++ks) {
      bf16x8 av[4], bv[4];
#pragma unroll
      for (int i = 0; i < 4; ++i) {
        int row = wr * 64 + i * 16 + l15;
        int ch = (ks * 4 + l4) ^ (row & 7);
        av[i] = *(const bf16x8*)((const char*)sA + row * 128 + ch * 16);
      }
#pragma unroll
      for (int i = 0; i < 4; ++i) {
        int row = wc * 64 + i * 16 + l15;
        int ch = (ks * 4 + l4) ^ (row & 7);
        bv[i] = *(const bf16x8*)((const char*)sB + row * 128 + ch * 16);
      }
#pragma unroll
      for (int mi = 0; mi < 4; ++mi)
#pragma unroll
        for (int ni = 0; ni < 4; ++ni)
          acc[mi][ni] = __builtin_amdgcn_mfma_f32_16x16x32_bf16(av[mi], bv[ni], acc[mi][ni], 0, 0, 0);
    }
  }
#pragma unroll
  for (int mi = 0; mi < 4; ++mi)
#pragma unroll
    for (int r = 0; r < 4; ++r) {
      long row = m0 + wr * 64 + mi * 16 + l4 * 4 + r;
#pragma unroll
      for (int ni = 0; ni < 4; ++ni) {
        long col = n0 + wc * 64 + ni * 16 + l15;
        if constexpr (CF32)
          ((float*)Cp)[row * (long)N + col] = acc[mi][ni][r];
        else
          ((__hip_bfloat16*)Cp)[row * (long)N + col] = __float2bfloat16(acc[mi][ni][r]);
      }
    }
}

// ---------------------------------------------------------------------------
// Same GEMM with BM=64 (grid 2x blocks) for the small-N out-projection:
// 4 waves side-by-side over N (each 64x32), acc[4][2]. fp32 C out.
// ---------------------------------------------------------------------------
__global__ __launch_bounds__(256) void gemm_bt64(const __hip_bfloat16* __restrict__ A,
                                                 const __hip_bfloat16* __restrict__ Bt,
                                                 float* __restrict__ C,
                                                 int M, int N, int K) {
  __shared__ short sA[64 * 64];
  __shared__ short sB[128 * 64];
  const int tid = threadIdx.x;
  const int lane = tid & 63;
  const int w = tid >> 6;
  const int l15 = lane & 15, l4 = lane >> 4;
  const long m0 = (long)blockIdx.y * 64, n0 = (long)blockIdx.x * 128;

  f32x4 acc[4][2] = {};

  for (int k0 = 0; k0 < K; k0 += 64) {
    __syncthreads();
#pragma unroll
    for (int c = 0; c < 2; ++c) {
      int ci = c * 256 + tid;
      int row = ci >> 3;
      int sc = (ci & 7) ^ (row & 7);
      load_lds16(A + (m0 + row) * (long)K + k0 + sc * 8, (char*)sA + c * 4096 + w * 1024);
    }
#pragma unroll
    for (int c = 0; c < 4; ++c) {
      int ci = c * 256 + tid;
      int row = ci >> 3;
      int sc = (ci & 7) ^ (row & 7);
      load_lds16(Bt + (n0 + row) * (long)K + k0 + sc * 8, (char*)sB + c * 4096 + w * 1024);
    }
    __syncthreads();
#pragma unroll
    for (int ks = 0; ks < 2; ++ks) {
      bf16x8 av[4], bv[2];
#pragma unroll
      for (int i = 0; i < 4; ++i) {
        int row = i * 16 + l15;
        int ch = (ks * 4 + l4) ^ (row & 7);
        av[i] = *(const bf16x8*)((const char*)sA + row * 128 + ch * 16);
      }
#pragma unroll
      for (int i = 0; i < 2; ++i) {
        int row = w * 32 + i * 16 + l15;
        int ch = (ks * 4 + l4) ^ (row & 7);
        bv[i] = *(const bf16x8*)((const char*)sB + row * 128 + ch * 16);
      }
#pragma unroll
      for (int mi = 0; mi < 4; ++mi)
#pragma unroll
        for (int ni = 0; ni < 2; ++ni)
          acc[mi][ni] = __builtin_amdgcn_mfma_f32_16x16x32_bf16(av[mi], bv[ni], acc[mi][ni], 0, 0, 0);
    }
  }
#pragma unroll
  for (int mi = 0; mi < 4; ++mi)
#pragma unroll
    for (int r = 0; r < 4; ++r) {
      long row = m0 + mi * 16 + l4 * 4 + r;
#pragma unroll
      for (int ni = 0; ni < 2; ++ni) {
        long col = n0 + w * 32 + ni * 16 + l15;
        C[row * (long)N + col] = acc[mi][ni][r];
      }
    }
}

// ---------------------------------------------------------------------------
// Flash attention, ALiBi + causal, exp2 domain, backward KV iteration.
// Round 11: SWAPPED QK^T — S^T = mfma(K, Q) so each lane owns ONE q-row
// (q = w*16+l15) with kv = nf*16+l4*4+r. Row-max = 15 in-reg fmax + 2
// shfl_xor; mrun is a scalar; P packs to LDS as 4x ds_write_b64 (r=0..3
// are consecutive kv). PV unchanged (b128 pf reads, P@ones rowsum MFMA).
// Single-buffer staging (round-8 pattern — dbuf regressed: LDS 43KB cut
// blocks/CU 4->3). Defer-max threshold 8 (exact, P <= 2^8).
// ---------------------------------------------------------------------------
__global__ __launch_bounds__(256) void attn_fwd(const __hip_bfloat16* __restrict__ qkv,
                                                __hip_bfloat16* __restrict__ O) {
  constexpr int T = 2048;
  constexpr int LDQ = 3072;
  const int b = blockIdx.x >> 4;
  const int h = blockIdx.x & 15;
  const int q0 = (31 - (int)blockIdx.y) * 64;
  const int tid = threadIdx.x;
  const int lane = tid & 63;
  const int w = tid >> 6;
  const int l15 = lane & 15, l4 = lane >> 4;

  __shared__ short sK[64 * 64];      // [kv][d], XOR chunk-swizzled
  __shared__ short sVT[64 * 72];     // [d][kv], stride 72
  __shared__ short sP[4][16 * 72];   // per-wave P [qloc][kv], stride 72

  const float sl2 = exp2f(-0.5f * (float)(h + 1)) * 1.44269504f;  // slope*log2e
  const long base_bt = (long)b * T;

  // Q fragments (B operand of swapped MFMA — same lane mapping as A),
  // pre-scaled by scale*log2e = 0.125*1.4427
  bf16x8 qf[2];
#pragma unroll
  for (int ks = 0; ks < 2; ++ks) {
    long qrow = base_bt + q0 + w * 16 + l15;
    bf16x8 v = *(const bf16x8*)(qkv + qrow * LDQ + h * 64 + ks * 32 + l4 * 8);
#pragma unroll
    for (int j = 0; j < 8; ++j)
      v[j] = f32_to_bf16_bits(bf16_bits_to_f32(v[j]) * 0.18033688f);
    qf[ks] = v;
  }

  // ALiBi per-reg invariant: kvloc = nf*16 + l4*4 + r
  f32x4 alinv[4];
#pragma unroll
  for (int nf = 0; nf < 4; ++nf)
#pragma unroll
    for (int r = 0; r < 4; ++r)
      alinv[nf][r] = sl2 * (float)(nf * 16 + l4 * 4 + r);

  bf16x8 ones;
#pragma unroll
  for (int j = 0; j < 8; ++j) ones[j] = (short)0x3F80;  // bf16 1.0

  f32x4 oacc[4] = {};                 // [nd], rows q=l4*4+r
  f32x4 lacc = {};                    // row-sum (P @ ones), rows q=l4*4+r
  float mrun = -1e30f;                // running max for row q = w*16+l15

  for (int kv0 = q0; kv0 >= 0; kv0 -= 64) {
    const bool masked = (kv0 == q0);   // only the diagonal tile
    __syncthreads();
    // stage K [64][64] via global_load_lds, pre-swizzled source
#pragma unroll
    for (int c = 0; c < 2; ++c) {
      int ci = c * 256 + tid;
      int row = ci >> 3;
      int sc = (ci & 7) ^ (row & 7);
      load_lds16(qkv + (base_bt + kv0 + row) * LDQ + 1024 + h * 64 + sc * 8,
                 (char*)sK + c * 4096 + w * 1024);
    }
    // stage V^T [64][72]
#pragma unroll
    for (int i = 0; i < 2; ++i) {
      int d0 = 8 * (w + 4 * i);
      bf16x8 v = *(const bf16x8*)(qkv + (base_bt + kv0 + lane) * LDQ + 2048 + h * 64 + d0);
#pragma unroll
      for (int j = 0; j < 8; ++j)
        sVT[(d0 + j) * 72 + lane] = v[j];
    }
    __syncthreads();

    // S^T = K @ Q^T + alibi C-init: lane holds [kv=nf*16+l4*4+r][q=w*16+l15]
    float skv0 = sl2 * (float)kv0;
    f32x4 s[4];
#pragma unroll
    for (int nf = 0; nf < 4; ++nf) {
#pragma unroll
      for (int r = 0; r < 4; ++r)
        s[nf][r] = alinv[nf][r] + skv0;
    }
#pragma unroll
    for (int ks = 0; ks < 2; ++ks) {
      bf16x8 kf[4];
#pragma unroll
      for (int nf = 0; nf < 4; ++nf) {
        int row = nf * 16 + l15;
        int ch = (ks * 4 + l4) ^ (row & 7);
        kf[nf] = *(const bf16x8*)((const char*)sK + row * 128 + ch * 16);
      }
#pragma unroll
      for (int nf = 0; nf < 4; ++nf)
        s[nf] = __builtin_amdgcn_mfma_f32_16x16x32_bf16(kf[nf], qf[ks], s[nf], 0, 0, 0);
    }

    // mask (diag tile only): keep kvloc <= qloc(=w*16+l15)
    if (masked) {
      int qloc = w * 16 + l15;
#pragma unroll
      for (int nf = 0; nf < 4; ++nf)
#pragma unroll
        for (int r = 0; r < 4; ++r)
          s[nf][r] = (nf * 16 + l4 * 4 + r <= qloc) ? s[nf][r] : -1e30f;
    }

    // row max: 16 in-register values, then reduce across the 4 l4-groups
    float mx = fmaxf(fmaxf(fmaxf(s[0][0], s[0][1]), fmaxf(s[0][2], s[0][3])),
                     fmaxf(fmaxf(s[1][0], s[1][1]), fmaxf(s[1][2], s[1][3])));
    float mx2 = fmaxf(fmaxf(fmaxf(s[2][0], s[2][1]), fmaxf(s[2][2], s[2][3])),
                      fmaxf(fmaxf(s[3][0], s[3][1]), fmaxf(s[3][2], s[3][3])));
    mx = fmaxf(mx, mx2);
    mx = fmaxf(mx, __shfl_xor(mx, 16, 64));
    mx = fmaxf(mx, __shfl_xor(mx, 32, 64));

    // defer-max, threshold 8 (exact: P <= 2^8)
    if (__any((mx > mrun + 8.f) ? 1 : 0)) {
      float mnew = fmaxf(mrun, mx);
      float f = exp2f(mrun - mnew);
      mrun = mnew;
      // oacc/lacc rows are q=l4*4+r, owned (softmax-wise) by lane l4*4+r
      float ff[4];
#pragma unroll
      for (int r = 0; r < 4; ++r)
        ff[r] = __shfl(f, l4 * 4 + r, 64);
#pragma unroll
      for (int r = 0; r < 4; ++r) {
        lacc[r] *= ff[r];
#pragma unroll
        for (int nd = 0; nd < 4; ++nd)
          oacc[nd][r] *= ff[r];
      }
    }

    // P = exp2(s - mrun) -> packed b64 writes (r=0..3 are consecutive kv)
#pragma unroll
    for (int nf = 0; nf < 4; ++nf) {
      unsigned p0 = (unsigned)(unsigned short)f32_to_bf16_bits(exp2f(s[nf][0] - mrun));
      unsigned p1 = (unsigned)(unsigned short)f32_to_bf16_bits(exp2f(s[nf][1] - mrun));
      unsigned p2 = (unsigned)(unsigned short)f32_to_bf16_bits(exp2f(s[nf][2] - mrun));
      unsigned p3 = (unsigned)(unsigned short)f32_to_bf16_bits(exp2f(s[nf][3] - mrun));
      uint2v u;
      u[0] = p0 | (p1 << 16);
      u[1] = p2 | (p3 << 16);
      *(uint2v*)(sP[w] + l15 * 72 + nf * 16 + l4 * 4) = u;
    }

    // fence per-wave sP writes before A-frag reads (rule 18)
    asm volatile("s_waitcnt lgkmcnt(0)" ::: "memory");
    __builtin_amdgcn_sched_barrier(0);

    // O += P @ V ; row-sum rides along as P @ ones
#pragma unroll
    for (int ks = 0; ks < 2; ++ks) {
      bf16x8 pf = *(const bf16x8*)(sP[w] + l15 * 72 + ks * 32 + l4 * 8);
      lacc = __builtin_amdgcn_mfma_f32_16x16x32_bf16(pf, ones, lacc, 0, 0, 0);
      bf16x8 vf[4];
#pragma unroll
      for (int nd = 0; nd < 4; ++nd)
        vf[nd] = *(const bf16x8*)(sVT + (nd * 16 + l15) * 72 + ks * 32 + l4 * 8);
#pragma unroll
      for (int nd = 0; nd < 4; ++nd)
        oacc[nd] = __builtin_amdgcn_mfma_f32_16x16x32_bf16(pf, vf[nd], oacc[nd], 0, 0, 0);
    }
  }

  // epilogue: O / rowsum (rows q=l4*4+r match lacc/oacc)
#pragma unroll
  for (int r = 0; r < 4; ++r) {
    long q = base_bt + q0 + w * 16 + l4 * 4 + r;
    float inv = 1.0f / lacc[r];
#pragma unroll
    for (int nd = 0; nd < 4; ++nd) {
      int d = nd * 16 + l15;
      O[q * 1024 + h * 64 + d] = __float2bfloat16(oacc[nd][r] * inv);
    }
  }
}

extern "C" void kernel_launch(void* const* d_in, const int* in_sizes, int n_in,
                              void* d_out, int out_size, void* d_ws, size_t ws_size,
                              hipStream_t stream) {
  const float* x    = (const float*)d_in[0];   // [4096,1024] fp32
  const float* Wqkv = (const float*)d_in[1];   // [3072,1024] fp32
  const float* Wout = (const float*)d_in[2];   // [1024,1024] fp32
  float* out = (float*)d_out;                  // [4096,1024] fp32

  // ws layout (shorts): x_bf16 | Wqkv_bf16 | Wout_bf16 | qkv_ws ; attn aliases x_bf16
  short* xb  = (short*)d_ws;                         // 4096*1024
  short* wqb = xb + 4194304;                         // 3072*1024
  short* wob = wqb + 3145728;                        // 1024*1024
  short* qkv = wob + 1048576;                        // 4096*3072
  short* attn = xb;                                  // alias: x_bf16 dead after GEMM1

  dim3 blk(256);
  conv_f32_bf16<<<8192, blk, 0, stream>>>((const float4*)x, (const float4*)Wqkv,
                                          (const float4*)Wout, (short4v*)xb,
                                          (short4v*)wqb, (short4v*)wob);
  // qkv = x @ W_qkv^T : M=4096 N=3072 K=1024
  gemm_bt<false><<<dim3(24, 32), blk, 0, stream>>>((const __hip_bfloat16*)xb,
                                                   (const __hip_bfloat16*)wqb,
                                                   qkv, 4096, 3072, 1024);
  // attention: grid (bh=32 fast, qtile=32 reversed)
  attn_fwd<<<dim3(32, 32), blk, 0, stream>>>((const __hip_bfloat16*)qkv,
                                             (__hip_bfloat16*)attn);
  // out = attn @ W_out^T : M=4096 N=1024 K=1024 (fp32 out), BM=64 tile
  gemm_bt64<<<dim3(8, 64), blk, 0, stream>>>((const __hip_bfloat16*)attn,
                                             (const __hip_bfloat16*)wob,
                                             out, 4096, 1024, 1024);
}